// Round 9
// baseline (198.739 us; speedup 1.0000x reference)
//
#include <hip/hip_runtime.h>
#include <cstdint>

// Problem constants (fixed shape from setup_inputs): x [4,64,512,512] f32
#define BATCH 4
#define CH    64
#define HWSZ  262144           // 512*512 = 2^18
#define NLOC  (BATCH*HWSZ)     // 1048576 locations
#define NB_STATS (NLOC/256)    // 4096 blocks, 256 locations each
#define NORM_BLOCKS ((BATCH*CH*HWSZ)/4/256)  // 65536
#define EPS_BN 1e-5f

// ===========================================================================
// MEASUREMENT ROUND: byte-identical to R3 (the 158.4 us best) EXCEPT the
// stats kernel is launched TWICE. stats is idempotent (all outputs are pure
// deterministic overwrites), so correctness and graph capture are unaffected;
// total_dur - 158.4 = exact stats duration. This resolves the stats/norm
// split that rocprof's top-5 (saturated by 1-GiB harness fills) hides.
// ===========================================================================

// ---------------------------------------------------------------------------
// Kernel 1: fused mask + per-channel partial sums. (R3 exact)
// Block = 256 threads = 4 waves, 256 consecutive locations.
// Wave q owns channels [16q,16q+16); lane l owns locations 4l..4l+3 (float4).
// Cross-lane reduction via LDS transpose: slds[64][67] (2-way aliasing, free).
// ---------------------------------------------------------------------------
__global__ __launch_bounds__(256) void stats_kernel(
    const float* __restrict__ x,
    float* __restrict__ psum,      // [NB_STATS][64]
    float* __restrict__ psumsq,    // [NB_STATS][64]
    float* __restrict__ pcount,    // [NB_STATS]
    unsigned char* __restrict__ maskout) // [NLOC]
{
    const int tid = threadIdx.x;
    const int q   = tid >> 6;          // wave id 0..3
    const int l   = tid & 63;          // lane id
    const int loc_base = blockIdx.x * 256;
    const int b       = loc_base >> 18;          // / HWSZ
    const int hw_base = loc_base & (HWSZ - 1);
    const int cbase   = q * 16;

    __shared__ unsigned int pmw[4][64];
    __shared__ float slds [64][67];
    __shared__ float s2lds[64][67];
    __shared__ float comb[2][4][64];

    // 16 coalesced float4 loads per lane (one per owned channel)
    const float* xb = x + ((size_t)b * CH) * HWSZ + hw_base + l * 4;
    float4 val[16];
#pragma unroll
    for (int i = 0; i < 16; ++i)
        val[i] = *(const float4*)(xb + (size_t)(cbase + i) * HWSZ);

    // partial mask nibble for this wave's 16 channels (bit j = loc 4l+j)
    unsigned int bits = 0;
#pragma unroll
    for (int i = 0; i < 16; ++i) {
        bits |= (val[i].x > 0.f ? 1u : 0u)
              | (val[i].y > 0.f ? 2u : 0u)
              | (val[i].z > 0.f ? 4u : 0u)
              | (val[i].w > 0.f ? 8u : 0u);
    }

    // OR nibbles across the 4 waves (all waves cover the same 256 locations)
    pmw[q][l] = bits;
    __syncthreads();
    const unsigned int allbits =
        pmw[0][l] | pmw[1][l] | pmw[2][l] | pmw[3][l];

    const float m0 = (allbits & 1u) ? 1.f : 0.f;
    const float m1 = (allbits & 2u) ? 1.f : 0.f;
    const float m2 = (allbits & 4u) ? 1.f : 0.f;
    const float m3 = (allbits & 8u) ? 1.f : 0.f;

    // wave 0: write mask bytes + block valid-count partial
    if (q == 0) {
        unsigned int packed = (allbits & 1u ? 1u : 0u)
                            | (allbits & 2u ? 0x100u : 0u)
                            | (allbits & 4u ? 0x10000u : 0u)
                            | (allbits & 8u ? 0x1000000u : 0u);
        *(unsigned int*)(maskout + loc_base + l * 4) = packed;

        float cnt = (float)__popc(allbits & 0xFu);
#pragma unroll
        for (int off = 32; off; off >>= 1)
            cnt += __shfl_xor(cnt, off, 64);
        if (l == 0) pcount[blockIdx.x] = cnt;
    }

    // per-thread per-channel masked partials -> LDS transpose buffers
#pragma unroll
    for (int i = 0; i < 16; ++i) {
        const float t0 = val[i].x * m0;
        const float t1 = val[i].y * m1;
        const float t2 = val[i].z * m2;
        const float t3 = val[i].w * m3;
        slds [cbase + i][l] = (t0 + t1) + (t2 + t3);
        s2lds[cbase + i][l] = (t0 * val[i].x + t1 * val[i].y)
                            + (t2 * val[i].z + t3 * val[i].w);
    }
    __syncthreads();

    // read phase: thread handles (channel c, quarter part); wave-uniform part
    {
        const int c    = tid & 63;
        const int part = tid >> 6;
        float s = 0.f, s2 = 0.f;
#pragma unroll
        for (int j = 0; j < 16; ++j) {
            s  += slds [c][part * 16 + j];
            s2 += s2lds[c][part * 16 + j];
        }
        comb[0][part][c] = s;
        comb[1][part][c] = s2;
    }
    __syncthreads();

    if (tid < 64) {
        const float fs  = (comb[0][0][tid] + comb[0][1][tid])
                        + (comb[0][2][tid] + comb[0][3][tid]);
        const float fs2 = (comb[1][0][tid] + comb[1][1][tid])
                        + (comb[1][2][tid] + comb[1][3][tid]);
        psum  [(size_t)blockIdx.x * 64 + tid] = fs;
        psumsq[(size_t)blockIdx.x * 64 + tid] = fs2;
    }
}

// ---------------------------------------------------------------------------
// Kernel 2: reduce 4096 partials per channel -> scale/shift. (R3 exact)
// ---------------------------------------------------------------------------
__global__ __launch_bounds__(256) void reduce_kernel(
    const float* __restrict__ psum,
    const float* __restrict__ psumsq,
    const float* __restrict__ pcount,
    const float* __restrict__ weight,
    const float* __restrict__ bias,
    float* __restrict__ scale,
    float* __restrict__ shift)
{
    const int c   = blockIdx.x;
    const int tid = threadIdx.x;
    float s = 0.f, s2 = 0.f, cn = 0.f;
    for (int i = tid; i < NB_STATS; i += 256) {
        s  += psum  [(size_t)i * 64 + c];
        s2 += psumsq[(size_t)i * 64 + c];
        cn += pcount[i];
    }
    __shared__ float ls[256], ls2[256], lc[256];
    ls[tid] = s; ls2[tid] = s2; lc[tid] = cn;
    __syncthreads();
#pragma unroll
    for (int off = 128; off; off >>= 1) {
        if (tid < off) {
            ls [tid] += ls [tid + off];
            ls2[tid] += ls2[tid + off];
            lc [tid] += lc [tid + off];
        }
        __syncthreads();
    }
    if (tid == 0) {
        const float cnt  = fmaxf(lc[0], 1.f);
        const float mean = ls[0] / cnt;
        const float var  = ls2[0] / cnt - mean * mean;
        const float inv  = rsqrtf(var + EPS_BN);
        const float wv   = weight[c];
        scale[c] = inv * wv;
        shift[c] = bias[c] - mean * inv * wv;
    }
}

// ---------------------------------------------------------------------------
// Kernel 3: normalize. (R3 exact)
// ---------------------------------------------------------------------------
__global__ __launch_bounds__(256) void norm_kernel(
    const float* __restrict__ x,
    const unsigned char* __restrict__ mask,
    const float* __restrict__ scale,
    const float* __restrict__ shift,
    float* __restrict__ out)
{
    const size_t t = (size_t)blockIdx.x * 256 + threadIdx.x;
    const size_t e = t * 4;                       // NCHW flat element index
    const int c  = (int)((e >> 18) & 63);         // (e / HWSZ) % CH
    const int b  = (int)(e >> 24);                // / (CH*HWSZ)
    const int hw = (int)(e & (HWSZ - 1));
    const int loc = (b << 18) | hw;

    const float4 v = *(const float4*)(x + e);
    const unsigned int mm = *(const unsigned int*)(mask + loc);
    const float sc = scale[c];
    const float sh = shift[c];

    float4 o;
    o.x = (mm & 0x000000FFu) ? fmaf(v.x, sc, sh) : v.x;
    o.y = (mm & 0x0000FF00u) ? fmaf(v.y, sc, sh) : v.y;
    o.z = (mm & 0x00FF0000u) ? fmaf(v.z, sc, sh) : v.z;
    o.w = (mm & 0xFF000000u) ? fmaf(v.w, sc, sh) : v.w;

    *(float4*)(out + e) = o;
}

// ---------------------------------------------------------------------------
extern "C" void kernel_launch(void* const* d_in, const int* in_sizes, int n_in,
                              void* d_out, int out_size, void* d_ws, size_t ws_size,
                              hipStream_t stream) {
    const float* x      = (const float*)d_in[0];
    const float* weight = (const float*)d_in[1];
    const float* bias   = (const float*)d_in[2];
    float* out = (float*)d_out;

    // workspace layout (all 4B-aligned): ~3.2 MB total
    float* psum   = (float*)d_ws;                    // 4096*64
    float* psumsq = psum   + (size_t)NB_STATS * 64;  // 4096*64
    float* pcount = psumsq + (size_t)NB_STATS * 64;  // 4096
    float* scale  = pcount + NB_STATS;               // 64
    float* shift  = scale + 64;                      // 64
    unsigned char* mask = (unsigned char*)(shift + 64); // NLOC bytes

    // stats launched TWICE (idempotent): T = T_R3 + stats_dur. Measurement.
    stats_kernel<<<NB_STATS, 256, 0, stream>>>(x, psum, psumsq, pcount, mask);
    stats_kernel<<<NB_STATS, 256, 0, stream>>>(x, psum, psumsq, pcount, mask);
    reduce_kernel<<<CH, 256, 0, stream>>>(psum, psumsq, pcount, weight, bias,
                                          scale, shift);
    norm_kernel<<<NORM_BLOCKS, 256, 0, stream>>>(x, mask, scale, shift, out);
}

// Round 10
// 163.416 us; speedup vs baseline: 1.2162x; 1.2162x over previous
//
#include <hip/hip_runtime.h>
#include <cstdint>

// Problem constants (fixed shape from setup_inputs): x [4,64,512,512] f32
#define BATCH 4
#define CH    64
#define HWSZ  262144           // 512*512 = 2^18
#define NLOC  (BATCH*HWSZ)     // 1048576 locations
#define NB_STATS (NLOC/256)    // 4096 blocks, 256 locations each
#define NORM_FPB 4096          // floats per norm block (one (b,c)-plane segment)
#define NORM_BLOCKS ((BATCH*CH*HWSZ)/NORM_FPB)  // 16384
#define EPS_BN 1e-5f

// ---------------------------------------------------------------------------
// Kernel 1: fused mask + per-channel partial sums. (R3 exact — measured at
// its 258 MB memory floor: 40.3 us via the R8 double-launch experiment.)
// ---------------------------------------------------------------------------
__global__ __launch_bounds__(256) void stats_kernel(
    const float* __restrict__ x,
    float* __restrict__ psum,      // [NB_STATS][64]
    float* __restrict__ psumsq,    // [NB_STATS][64]
    float* __restrict__ pcount,    // [NB_STATS]
    unsigned char* __restrict__ maskout) // [NLOC]
{
    const int tid = threadIdx.x;
    const int q   = tid >> 6;          // wave id 0..3
    const int l   = tid & 63;          // lane id
    const int loc_base = blockIdx.x * 256;
    const int b       = loc_base >> 18;          // / HWSZ
    const int hw_base = loc_base & (HWSZ - 1);
    const int cbase   = q * 16;

    __shared__ unsigned int pmw[4][64];
    __shared__ float slds [64][67];
    __shared__ float s2lds[64][67];
    __shared__ float comb[2][4][64];

    // 16 coalesced float4 loads per lane (one per owned channel)
    const float* xb = x + ((size_t)b * CH) * HWSZ + hw_base + l * 4;
    float4 val[16];
#pragma unroll
    for (int i = 0; i < 16; ++i)
        val[i] = *(const float4*)(xb + (size_t)(cbase + i) * HWSZ);

    // partial mask nibble for this wave's 16 channels (bit j = loc 4l+j)
    unsigned int bits = 0;
#pragma unroll
    for (int i = 0; i < 16; ++i) {
        bits |= (val[i].x > 0.f ? 1u : 0u)
              | (val[i].y > 0.f ? 2u : 0u)
              | (val[i].z > 0.f ? 4u : 0u)
              | (val[i].w > 0.f ? 8u : 0u);
    }

    // OR nibbles across the 4 waves (all waves cover the same 256 locations)
    pmw[q][l] = bits;
    __syncthreads();
    const unsigned int allbits =
        pmw[0][l] | pmw[1][l] | pmw[2][l] | pmw[3][l];

    const float m0 = (allbits & 1u) ? 1.f : 0.f;
    const float m1 = (allbits & 2u) ? 1.f : 0.f;
    const float m2 = (allbits & 4u) ? 1.f : 0.f;
    const float m3 = (allbits & 8u) ? 1.f : 0.f;

    // wave 0: write mask bytes + block valid-count partial
    if (q == 0) {
        unsigned int packed = (allbits & 1u ? 1u : 0u)
                            | (allbits & 2u ? 0x100u : 0u)
                            | (allbits & 4u ? 0x10000u : 0u)
                            | (allbits & 8u ? 0x1000000u : 0u);
        *(unsigned int*)(maskout + loc_base + l * 4) = packed;

        float cnt = (float)__popc(allbits & 0xFu);
#pragma unroll
        for (int off = 32; off; off >>= 1)
            cnt += __shfl_xor(cnt, off, 64);
        if (l == 0) pcount[blockIdx.x] = cnt;
    }

    // per-thread per-channel masked partials -> LDS transpose buffers
#pragma unroll
    for (int i = 0; i < 16; ++i) {
        const float t0 = val[i].x * m0;
        const float t1 = val[i].y * m1;
        const float t2 = val[i].z * m2;
        const float t3 = val[i].w * m3;
        slds [cbase + i][l] = (t0 + t1) + (t2 + t3);
        s2lds[cbase + i][l] = (t0 * val[i].x + t1 * val[i].y)
                            + (t2 * val[i].z + t3 * val[i].w);
    }
    __syncthreads();

    // read phase: thread handles (channel c, quarter part); wave-uniform part
    {
        const int c    = tid & 63;
        const int part = tid >> 6;
        float s = 0.f, s2 = 0.f;
#pragma unroll
        for (int j = 0; j < 16; ++j) {
            s  += slds [c][part * 16 + j];
            s2 += s2lds[c][part * 16 + j];
        }
        comb[0][part][c] = s;
        comb[1][part][c] = s2;
    }
    __syncthreads();

    if (tid < 64) {
        const float fs  = (comb[0][0][tid] + comb[0][1][tid])
                        + (comb[0][2][tid] + comb[0][3][tid]);
        const float fs2 = (comb[1][0][tid] + comb[1][1][tid])
                        + (comb[1][2][tid] + comb[1][3][tid]);
        psum  [(size_t)blockIdx.x * 64 + tid] = fs;
        psumsq[(size_t)blockIdx.x * 64 + tid] = fs2;
    }
}

// ---------------------------------------------------------------------------
// Kernel 2: reduce 4096 partials per channel -> scale/shift. (R3 exact)
// ---------------------------------------------------------------------------
__global__ __launch_bounds__(256) void reduce_kernel(
    const float* __restrict__ psum,
    const float* __restrict__ psumsq,
    const float* __restrict__ pcount,
    const float* __restrict__ weight,
    const float* __restrict__ bias,
    float* __restrict__ scale,
    float* __restrict__ shift)
{
    const int c   = blockIdx.x;
    const int tid = threadIdx.x;
    float s = 0.f, s2 = 0.f, cn = 0.f;
    for (int i = tid; i < NB_STATS; i += 256) {
        s  += psum  [(size_t)i * 64 + c];
        s2 += psumsq[(size_t)i * 64 + c];
        cn += pcount[i];
    }
    __shared__ float ls[256], ls2[256], lc[256];
    ls[tid] = s; ls2[tid] = s2; lc[tid] = cn;
    __syncthreads();
#pragma unroll
    for (int off = 128; off; off >>= 1) {
        if (tid < off) {
            ls [tid] += ls [tid + off];
            ls2[tid] += ls2[tid + off];
            lc [tid] += lc [tid + off];
        }
        __syncthreads();
    }
    if (tid == 0) {
        const float cnt  = fmaxf(lc[0], 1.f);
        const float mean = ls[0] / cnt;
        const float var  = ls2[0] / cnt - mean * mean;
        const float inv  = rsqrtf(var + EPS_BN);
        const float wv   = weight[c];
        scale[c] = inv * wv;
        shift[c] = bias[c] - mean * inv * wv;
    }
}

// ---------------------------------------------------------------------------
// Kernel 3: normalize, ILP-4 version (the one change this round).
// Block = 256 threads processes 4096 contiguous floats of ONE (b,c) plane:
// c is block-uniform (scale/shift loaded once), thread t handles 4 float4s
// at t*4 + i*1024. All 8 loads (4 x + 4 mask) are independent and issue
// before the first store -> 4x the in-flight bytes of the 1-float4 version,
// hiding HBM latency + block-turnaround that capped R3's norm at ~4.8 TB/s.
// ---------------------------------------------------------------------------
__global__ __launch_bounds__(256) void norm_kernel(
    const float* __restrict__ x,
    const unsigned char* __restrict__ mask,
    const float* __restrict__ scale,
    const float* __restrict__ shift,
    float* __restrict__ out)
{
    const size_t base = (size_t)blockIdx.x * NORM_FPB;  // flat float index
    const int c   = (int)((base >> 18) & 63);           // block-uniform
    const int b   = (int)(base >> 24);
    const int hw0 = (int)(base & (HWSZ - 1));
    const int loc0 = (b << 18) | hw0;
    const int t4  = threadIdx.x * 4;

    const float sc = scale[c];
    const float sh = shift[c];

    const float* xb = x + base + t4;
    float* ob = out + base + t4;
    const unsigned char* mb = mask + loc0 + t4;

    float4 v[4];
    unsigned int mm[4];
#pragma unroll
    for (int i = 0; i < 4; ++i) {
        v[i]  = *(const float4*)(xb + i * 1024);
        mm[i] = *(const unsigned int*)(mb + i * 1024);
    }

#pragma unroll
    for (int i = 0; i < 4; ++i) {
        float4 o;
        o.x = (mm[i] & 0x000000FFu) ? fmaf(v[i].x, sc, sh) : v[i].x;
        o.y = (mm[i] & 0x0000FF00u) ? fmaf(v[i].y, sc, sh) : v[i].y;
        o.z = (mm[i] & 0x00FF0000u) ? fmaf(v[i].z, sc, sh) : v[i].z;
        o.w = (mm[i] & 0xFF000000u) ? fmaf(v[i].w, sc, sh) : v[i].w;
        *(float4*)(ob + i * 1024) = o;
    }
}

// ---------------------------------------------------------------------------
extern "C" void kernel_launch(void* const* d_in, const int* in_sizes, int n_in,
                              void* d_out, int out_size, void* d_ws, size_t ws_size,
                              hipStream_t stream) {
    const float* x      = (const float*)d_in[0];
    const float* weight = (const float*)d_in[1];
    const float* bias   = (const float*)d_in[2];
    float* out = (float*)d_out;

    // workspace layout (all 4B-aligned): ~3.2 MB total
    float* psum   = (float*)d_ws;                    // 4096*64
    float* psumsq = psum   + (size_t)NB_STATS * 64;  // 4096*64
    float* pcount = psumsq + (size_t)NB_STATS * 64;  // 4096
    float* scale  = pcount + NB_STATS;               // 64
    float* shift  = scale + 64;                      // 64
    unsigned char* mask = (unsigned char*)(shift + 64); // NLOC bytes

    stats_kernel<<<NB_STATS, 256, 0, stream>>>(x, psum, psumsq, pcount, mask);
    reduce_kernel<<<CH, 256, 0, stream>>>(psum, psumsq, pcount, weight, bias,
                                          scale, shift);
    norm_kernel<<<NORM_BLOCKS, 256, 0, stream>>>(x, mask, scale, shift, out);
}

// Round 11
// 130.878 us; speedup vs baseline: 1.5185x; 1.2486x over previous
//
#include <hip/hip_runtime.h>
#include <cstdint>

// Problem constants (fixed shape from setup_inputs): x [4,64,512,512] f32
#define BATCH 4
#define CH    64
#define HWSZ  262144           // 512*512 = 2^18
#define NLOC  (BATCH*HWSZ)     // 1048576 locations
#define NB_STATS (NLOC/256)    // 4096 blocks, 256 locations each
#define NORM_BLOCKS ((BATCH*CH*HWSZ)/4/256)  // 65536
#define EPS_BN 1e-5f

typedef float f32x4 __attribute__((ext_vector_type(4)));

// ---------------------------------------------------------------------------
// Kernel 1: fused mask + per-channel partial sums. (R3 exact — measured at
// its 258 MB memory floor: 40.3 us via the R8 double-launch experiment.)
// ---------------------------------------------------------------------------
__global__ __launch_bounds__(256) void stats_kernel(
    const float* __restrict__ x,
    float* __restrict__ psum,      // [NB_STATS][64]
    float* __restrict__ psumsq,    // [NB_STATS][64]
    float* __restrict__ pcount,    // [NB_STATS]
    unsigned char* __restrict__ maskout) // [NLOC]
{
    const int tid = threadIdx.x;
    const int q   = tid >> 6;          // wave id 0..3
    const int l   = tid & 63;          // lane id
    const int loc_base = blockIdx.x * 256;
    const int b       = loc_base >> 18;          // / HWSZ
    const int hw_base = loc_base & (HWSZ - 1);
    const int cbase   = q * 16;

    __shared__ unsigned int pmw[4][64];
    __shared__ float slds [64][67];
    __shared__ float s2lds[64][67];
    __shared__ float comb[2][4][64];

    // 16 coalesced float4 loads per lane (one per owned channel)
    const float* xb = x + ((size_t)b * CH) * HWSZ + hw_base + l * 4;
    float4 val[16];
#pragma unroll
    for (int i = 0; i < 16; ++i)
        val[i] = *(const float4*)(xb + (size_t)(cbase + i) * HWSZ);

    // partial mask nibble for this wave's 16 channels (bit j = loc 4l+j)
    unsigned int bits = 0;
#pragma unroll
    for (int i = 0; i < 16; ++i) {
        bits |= (val[i].x > 0.f ? 1u : 0u)
              | (val[i].y > 0.f ? 2u : 0u)
              | (val[i].z > 0.f ? 4u : 0u)
              | (val[i].w > 0.f ? 8u : 0u);
    }

    // OR nibbles across the 4 waves (all waves cover the same 256 locations)
    pmw[q][l] = bits;
    __syncthreads();
    const unsigned int allbits =
        pmw[0][l] | pmw[1][l] | pmw[2][l] | pmw[3][l];

    const float m0 = (allbits & 1u) ? 1.f : 0.f;
    const float m1 = (allbits & 2u) ? 1.f : 0.f;
    const float m2 = (allbits & 4u) ? 1.f : 0.f;
    const float m3 = (allbits & 8u) ? 1.f : 0.f;

    // wave 0: write mask bytes + block valid-count partial
    if (q == 0) {
        unsigned int packed = (allbits & 1u ? 1u : 0u)
                            | (allbits & 2u ? 0x100u : 0u)
                            | (allbits & 4u ? 0x10000u : 0u)
                            | (allbits & 8u ? 0x1000000u : 0u);
        *(unsigned int*)(maskout + loc_base + l * 4) = packed;

        float cnt = (float)__popc(allbits & 0xFu);
#pragma unroll
        for (int off = 32; off; off >>= 1)
            cnt += __shfl_xor(cnt, off, 64);
        if (l == 0) pcount[blockIdx.x] = cnt;
    }

    // per-thread per-channel masked partials -> LDS transpose buffers
#pragma unroll
    for (int i = 0; i < 16; ++i) {
        const float t0 = val[i].x * m0;
        const float t1 = val[i].y * m1;
        const float t2 = val[i].z * m2;
        const float t3 = val[i].w * m3;
        slds [cbase + i][l] = (t0 + t1) + (t2 + t3);
        s2lds[cbase + i][l] = (t0 * val[i].x + t1 * val[i].y)
                            + (t2 * val[i].z + t3 * val[i].w);
    }
    __syncthreads();

    // read phase: thread handles (channel c, quarter part); wave-uniform part
    {
        const int c    = tid & 63;
        const int part = tid >> 6;
        float s = 0.f, s2 = 0.f;
#pragma unroll
        for (int j = 0; j < 16; ++j) {
            s  += slds [c][part * 16 + j];
            s2 += s2lds[c][part * 16 + j];
        }
        comb[0][part][c] = s;
        comb[1][part][c] = s2;
    }
    __syncthreads();

    if (tid < 64) {
        const float fs  = (comb[0][0][tid] + comb[0][1][tid])
                        + (comb[0][2][tid] + comb[0][3][tid]);
        const float fs2 = (comb[1][0][tid] + comb[1][1][tid])
                        + (comb[1][2][tid] + comb[1][3][tid]);
        psum  [(size_t)blockIdx.x * 64 + tid] = fs;
        psumsq[(size_t)blockIdx.x * 64 + tid] = fs2;
    }
}

// ---------------------------------------------------------------------------
// Kernel 2: reduce 4096 partials per channel -> scale/shift. (R3 exact)
// ---------------------------------------------------------------------------
__global__ __launch_bounds__(256) void reduce_kernel(
    const float* __restrict__ psum,
    const float* __restrict__ psumsq,
    const float* __restrict__ pcount,
    const float* __restrict__ weight,
    const float* __restrict__ bias,
    float* __restrict__ scale,
    float* __restrict__ shift)
{
    const int c   = blockIdx.x;
    const int tid = threadIdx.x;
    float s = 0.f, s2 = 0.f, cn = 0.f;
    for (int i = tid; i < NB_STATS; i += 256) {
        s  += psum  [(size_t)i * 64 + c];
        s2 += psumsq[(size_t)i * 64 + c];
        cn += pcount[i];
    }
    __shared__ float ls[256], ls2[256], lc[256];
    ls[tid] = s; ls2[tid] = s2; lc[tid] = cn;
    __syncthreads();
#pragma unroll
    for (int off = 128; off; off >>= 1) {
        if (tid < off) {
            ls [tid] += ls [tid + off];
            ls2[tid] += ls2[tid + off];
            lc [tid] += lc [tid + off];
        }
        __syncthreads();
    }
    if (tid == 0) {
        const float cnt  = fmaxf(lc[0], 1.f);
        const float mean = ls[0] / cnt;
        const float var  = ls2[0] / cnt - mean * mean;
        const float inv  = rsqrtf(var + EPS_BN);
        const float wv   = weight[c];
        scale[c] = inv * wv;
        shift[c] = bias[c] - mean * inv * wv;
    }
}

// ---------------------------------------------------------------------------
// Kernel 3: normalize = R3 structure + TWO cache-side changes:
//  (1) NONTEMPORAL stores: out is write-once/never-re-read; NT stops the
//      268 MB out-stream from allocating in L2/L3 and evicting x.
//  (2) REVERSED block order: stats streamed x through the 256 MiB L3
//      forward; reading back-to-front starts on the freshest resident lines,
//      and (with stores no longer allocating) L3 hits don't self-evict.
//  R5 tested (2) alone = null BECAUSE the store stream was churning L3;
//  this round removes that confound.
// ---------------------------------------------------------------------------
__global__ __launch_bounds__(256) void norm_kernel(
    const float* __restrict__ x,
    const unsigned char* __restrict__ mask,
    const float* __restrict__ scale,
    const float* __restrict__ shift,
    float* __restrict__ out)
{
    const int rb = (NORM_BLOCKS - 1) - (int)blockIdx.x;   // reversed order
    const size_t t = (size_t)rb * 256 + threadIdx.x;
    const size_t e = t * 4;                       // NCHW flat element index
    const int c  = (int)((e >> 18) & 63);         // (e / HWSZ) % CH
    const int b  = (int)(e >> 24);                // / (CH*HWSZ)
    const int hw = (int)(e & (HWSZ - 1));
    const int loc = (b << 18) | hw;

    const f32x4 v = *(const f32x4*)(x + e);
    const unsigned int mm = *(const unsigned int*)(mask + loc);
    const float sc = scale[c];
    const float sh = shift[c];

    f32x4 o;
    o.x = (mm & 0x000000FFu) ? fmaf(v.x, sc, sh) : v.x;
    o.y = (mm & 0x0000FF00u) ? fmaf(v.y, sc, sh) : v.y;
    o.z = (mm & 0x00FF0000u) ? fmaf(v.z, sc, sh) : v.z;
    o.w = (mm & 0xFF000000u) ? fmaf(v.w, sc, sh) : v.w;

    __builtin_nontemporal_store(o, (f32x4*)(out + e));
}

// ---------------------------------------------------------------------------
extern "C" void kernel_launch(void* const* d_in, const int* in_sizes, int n_in,
                              void* d_out, int out_size, void* d_ws, size_t ws_size,
                              hipStream_t stream) {
    const float* x      = (const float*)d_in[0];
    const float* weight = (const float*)d_in[1];
    const float* bias   = (const float*)d_in[2];
    float* out = (float*)d_out;

    // workspace layout (all 4B-aligned): ~3.2 MB total
    float* psum   = (float*)d_ws;                    // 4096*64
    float* psumsq = psum   + (size_t)NB_STATS * 64;  // 4096*64
    float* pcount = psumsq + (size_t)NB_STATS * 64;  // 4096
    float* scale  = pcount + NB_STATS;               // 64
    float* shift  = scale + 64;                      // 64
    unsigned char* mask = (unsigned char*)(shift + 64); // NLOC bytes

    stats_kernel<<<NB_STATS, 256, 0, stream>>>(x, psum, psumsq, pcount, mask);
    reduce_kernel<<<CH, 256, 0, stream>>>(psum, psumsq, pcount, weight, bias,
                                          scale, shift);
    norm_kernel<<<NORM_BLOCKS, 256, 0, stream>>>(x, mask, scale, shift, out);
}